// Round 21
// baseline (270.485 us; speedup 1.0000x reference)
//
#include <hip/hip_runtime.h>
#include <hip/hip_fp16.h>

#define BB 4
#define CC 32
#define HH 480
#define WW 640
#define HWv (HH*WW)

union H8 { __half h[8]; float4 f4; };
union H4 { short4 s; __half h[4]; };

// ---------------------------------------------------------------------------
// Kernel 1: 3x3 conv (32->8) + bias + affinity normalization, fused.
// VMEM-minimal variant: 4 px/thread -> each row window is ONE aligned
// float4 (3 VMEM/channel vs R9's 12). x-halos via __shfl_up/down of
// neighbor lanes; only tx==0/31 lanes issue a masked 1-lane edge load.
// Cross-ty shfl pollution at the wave's 32-lane seam is overridden by the
// edge-lane path. Branchless row masks (R3-proven numerics).
// Grid 2400x128 = 4800 waves = 4.7/SIMD.
// K stored fp16 (R9-proven). Output: K [B][9][H][W] fp16.
// ---------------------------------------------------------------------------
__global__ __launch_bounds__(128) void conv_gen(const float* __restrict__ kx,
                                                const float* __restrict__ Wf,
                                                const float* __restrict__ bf,
                                                __half* __restrict__ K)
{
    const int t  = threadIdx.x;
    const int tx = t & 31;              // 4-px column group in 128-px tile
    const int ty = t >> 5;              // row 0..3
    int blk = blockIdx.x;
    const int xt = blk % (WW / 128); blk /= (WW / 128);   // 5 x-tiles
    const int yt = blk % (HH / 4);                         // 120 y-tiles
    const int b  = blk / (HH / 4);
    const int y  = yt * 4 + ty;
    const int x0 = xt * 128 + 4 * tx;

    float acc[8][4];
#pragma unroll
    for (int o = 0; o < 8; ++o) {
        float bv = bf[o];
#pragma unroll
        for (int p = 0; p < 4; ++p) acc[o][p] = bv;
    }

    const float* kxb = kx + (size_t)b * CC * HWv + (size_t)y * WW + x0;

    const bool xm = (x0 > 0);
    const bool xp = (x0 + 4 < WW);
    const float xmf = xm ? 1.f : 0.f;
    const float xpf = xp ? 1.f : 0.f;
    const int eoffl = xm ? -1 : 0;      // clamped, always in-bounds
    const int eoffr = xp ?  4 : 3;

    int   rowoff[3];
    float mc[3];
#pragma unroll
    for (int r = 0; r < 3; ++r) {
        int dy = r - 1;
        bool ok = (y + dy >= 0) && (y + dy < HH);
        rowoff[r] = ok ? dy * WW : 0;   // clamped: stays in-plane
        mc[r] = ok ? 1.f : 0.f;
    }

#pragma unroll 1
    for (int c = 0; c < CC; ++c) {
        const float* pl = kxb + (size_t)c * HWv;

        float row[3][6];
#pragma unroll
        for (int r = 0; r < 3; ++r) {
            const float* rp = pl + rowoff[r];
            float4 v = *reinterpret_cast<const float4*>(rp);   // 16B aligned
            float lv = __shfl_up(v.w, 1);       // neighbor's x0-1
            float rv = __shfl_down(v.x, 1);     // neighbor's x0+4
            if (tx == 0)  lv = rp[eoffl] * xmf; // tile edge: masked 1-lane load
            if (tx == 31) rv = rp[eoffr] * xpf;
            row[r][0] = lv  * mc[r];
            row[r][1] = v.x * mc[r]; row[r][2] = v.y * mc[r];
            row[r][3] = v.z * mc[r]; row[r][4] = v.w * mc[r];
            row[r][5] = rv  * mc[r];
        }

#pragma unroll
        for (int o = 0; o < 8; ++o) {
#pragma unroll
            for (int r = 0; r < 3; ++r) {
#pragma unroll
                for (int s = 0; s < 3; ++s) {
                    // wave-uniform index -> s_load -> SGPR operand in v_fma
                    float wv = Wf[((o * CC + c) * 3 + r) * 3 + s];
#pragma unroll
                    for (int p = 0; p < 4; ++p) acc[o][p] += wv * row[r][p + s];
                }
            }
        }
    }

    // ---- normalization: a = aff / sum|aff|; K0 = 1 - sum(a) ----
    float k0[4];
#pragma unroll
    for (int p = 0; p < 4; ++p) {
        float asum = 0.f;
#pragma unroll
        for (int o = 0; o < 8; ++o) asum += fabsf(acc[o][p]);
        float rinv = 1.0f / asum;
        float s = 0.f;
#pragma unroll
        for (int o = 0; o < 8; ++o) { acc[o][p] *= rinv; s += acc[o][p]; }
        k0[p] = 1.0f - s;
    }

    size_t base = (size_t)b * 9 * HWv + (size_t)y * WW + x0;
    {
        H4 u;
#pragma unroll
        for (int p = 0; p < 4; ++p) u.h[p] = __float2half(k0[p]);
        *reinterpret_cast<short4*>(K + base) = u.s;
    }
#pragma unroll
    for (int o = 0; o < 8; ++o) {
        H4 u;
#pragma unroll
        for (int p = 0; p < 4; ++p) u.h[p] = __float2half(acc[o][p]);
        *reinterpret_cast<short4*>(K + base + (size_t)(o + 1) * HWv) = u.s;
    }
}

// ---------------------------------------------------------------------------
// Kernel 2: one propagation iteration, templated on x dtype (R16-proven;
// at the streaming-BW roofline: ~27 MB/launch @ ~6.3 TB/s effective).
// Iter 0: f32 -> fp16;  1..10: fp16 -> fp16;  11: fp16 -> f32 d_out.
// OFFSETS order: (0,0),(0,1),(0,-1),(1,0),(1,1),(1,-1),(-1,0),(-1,1),(-1,-1)
// ---------------------------------------------------------------------------
__device__ __forceinline__ void load_row6(const float* r, bool rowok, bool xm,
                                          bool xpl, float o[6])
{
    if (rowok) {
        float4 v = *reinterpret_cast<const float4*>(r);
        o[0] = xm ? r[-1] : 0.f;
        o[1] = v.x; o[2] = v.y; o[3] = v.z; o[4] = v.w;
        o[5] = xpl ? r[4] : 0.f;
    } else {
#pragma unroll
        for (int q = 0; q < 6; ++q) o[q] = 0.f;
    }
}

__device__ __forceinline__ void load_row6h(const __half* r, bool rowok, bool xm,
                                           bool xpl, float o[6])
{
    if (rowok) {
        H4 u;
        u.s = *reinterpret_cast<const short4*>(r);     // 8 B, aligned (x0%4==0)
        o[0] = xm ? __half2float(r[-1]) : 0.f;
        o[1] = __half2float(u.h[0]); o[2] = __half2float(u.h[1]);
        o[3] = __half2float(u.h[2]); o[4] = __half2float(u.h[3]);
        o[5] = xpl ? __half2float(r[4]) : 0.f;
    } else {
#pragma unroll
        for (int q = 0; q < 6; ++q) o[q] = 0.f;
    }
}

template <typename TI, typename TO>
__global__ __launch_bounds__(256) void prop(const TI* __restrict__ xin,
                                            const __half* __restrict__ K,
                                            TO* __restrict__ xout)
{
    int tid = blockIdx.x * 256 + threadIdx.x;
    const int XT = WW / 4;
    int x4 = tid % XT;
    int t2 = tid / XT;
    int y  = t2 % HH;
    int b  = t2 / HH;
    if (b >= BB) return;
    int x0 = x4 * 4;

    const bool xm  = (x0 > 0);
    const bool xpl = (x0 + 4 < WW);

    const TI* xb = xin + (size_t)b * HWv + (size_t)y * WW + x0;
    float rm[6], r0[6], rp[6];
    if constexpr (sizeof(TI) == 4) {
        load_row6((const float*)xb - WW, y > 0,      xm, xpl, rm);
        load_row6((const float*)xb,      true,       xm, xpl, r0);
        load_row6((const float*)xb + WW, y < HH - 1, xm, xpl, rp);
    } else {
        load_row6h((const __half*)xb - WW, y > 0,      xm, xpl, rm);
        load_row6h((const __half*)xb,      true,       xm, xpl, r0);
        load_row6h((const __half*)xb + WW, y < HH - 1, xm, xpl, rp);
    }

    const __half* Kb = K + (size_t)b * 9 * HWv + (size_t)y * WW + x0;
    float kv[9][4];
#pragma unroll
    for (int k = 0; k < 9; ++k) {
        H4 u;
        u.s = *reinterpret_cast<const short4*>(Kb + (size_t)k * HWv);  // 8 B
#pragma unroll
        for (int p = 0; p < 4; ++p) kv[k][p] = __half2float(u.h[p]);
    }

    float o4[4];
#pragma unroll
    for (int p = 0; p < 4; ++p) {
        o4[p] = kv[0][p] * r0[p + 1]
              + kv[1][p] * r0[p]
              + kv[2][p] * r0[p + 2]
              + kv[3][p] * rm[p + 1]
              + kv[4][p] * rm[p]
              + kv[5][p] * rm[p + 2]
              + kv[6][p] * rp[p + 1]
              + kv[7][p] * rp[p]
              + kv[8][p] * rp[p + 2];
    }

    TO* ob = xout + (size_t)b * HWv + (size_t)y * WW + x0;
    if constexpr (sizeof(TO) == 4) {
        *reinterpret_cast<float4*>((float*)ob) =
            make_float4(o4[0], o4[1], o4[2], o4[3]);
    } else {
        H4 u;
#pragma unroll
        for (int p = 0; p < 4; ++p) u.h[p] = __float2half(o4[p]);
        *reinterpret_cast<short4*>((__half*)ob) = u.s;
    }
}

// ---------------------------------------------------------------------------
extern "C" void kernel_launch(void* const* d_in, const int* in_sizes, int n_in,
                              void* d_out, int out_size, void* d_ws, size_t ws_size,
                              hipStream_t stream) {
    const float* kx   = (const float*)d_in[0];   // [4,32,480,640]
    const float* x_in = (const float*)d_in[1];   // [4,1,480,640]
    const float* Wf   = (const float*)d_in[2];   // [8,32,3,3]
    const float* bf   = (const float*)d_in[3];   // [8]
    float* out  = (float*)d_out;                 // [4,1,480,640]

    __half* Kbuf = (__half*)d_ws;                         // 22.12 MB fp16
    __half* xh0  = Kbuf + (size_t)9 * BB * HWv;           // 2.46 MB fp16
    __half* xh1  = xh0  + (size_t)BB * HWv;               // 2.46 MB fp16
    __half* ping[2] = { xh0, xh1 };

    // conv: 4 px/thread, block=128 -> 2400 blocks (4800 waves, 4.7/SIMD)
    const int cblocks = BB * (HH / 4) * (WW / 128);       // 2400
    conv_gen<<<cblocks, 128, 0, stream>>>(kx, Wf, bf, Kbuf);

    // prop: 12 launches; intermediates fp16
    const int pblocks = BB * HH * (WW / 4) / 256;         // 1200

    prop<float, __half><<<pblocks, 256, 0, stream>>>(x_in, Kbuf, ping[0]);
    for (int it = 1; it <= 10; ++it) {
        prop<__half, __half><<<pblocks, 256, 0, stream>>>(
            ping[(it - 1) & 1], Kbuf, ping[it & 1]);
    }
    prop<__half, float><<<pblocks, 256, 0, stream>>>(ping[0], Kbuf, out);
}

// Round 22
// 159.974 us; speedup vs baseline: 1.6908x; 1.6908x over previous
//
#include <hip/hip_runtime.h>
#include <hip/hip_fp16.h>

#define BB 4
#define CC 32
#define HH 480
#define WW 640
#define HWv (HH*WW)

union H8 { __half h[8]; float4 f4; };
union H4 { short4 s; __half h[4]; };

// ---------------------------------------------------------------------------
// Kernel 1: 3x3 conv (32->8) + bias + affinity normalization, fused.
// Exact R9/R16 structure — measured best (108 us), reproduced twice.
// Ten alternative conv structures (ILP x2/x4, TLP x2, branchless, hoisted
// loads, LDS staging x2, LDS weights, fp16 dot2, MFMA x2, shfl-minimal-VMEM)
// all regressed or tied. No pipe saturates (43% VALU / 24% HBM / 0 LDS):
// the per-channel compiler-scheduled load->FMA chain is the empirical
// HIP-source-level floor for this shape.
// K stored fp16 (halves prop's dominant traffic; absmax 256 << 1111).
// Output: K [B][9][H][W] fp16, K[0] = 1 - sum(a), K[1..8] = aff_k / sum|aff|
// ---------------------------------------------------------------------------
__global__ __launch_bounds__(128) void conv_gen(const float* __restrict__ kx,
                                                const float* __restrict__ Wf,
                                                const float* __restrict__ bf,
                                                __half* __restrict__ K)
{
    int tid = blockIdx.x * 128 + threadIdx.x;
    const int XT = WW / 8;              // 80 thread-columns
    int x8 = tid % XT;
    int t2 = tid / XT;
    int y  = t2 % HH;
    int b  = t2 / HH;
    if (b >= BB) return;
    int x0 = x8 * 8;

    float acc[8][8];
#pragma unroll
    for (int o = 0; o < 8; ++o) {
        float bv = bf[o];
#pragma unroll
        for (int p = 0; p < 8; ++p) acc[o][p] = bv;
    }

    const float* kxb = kx + (size_t)b * CC * HWv + (size_t)y * WW + x0;
    const bool xm = (x0 > 0);
    const bool xp = (x0 + 8 < WW);

    for (int c = 0; c < CC; ++c) {
        const float* pl = kxb + (size_t)c * HWv;
#pragma unroll
        for (int r = 0; r < 3; ++r) {
            const int dy = r - 1;
            const bool rowok = (y + dy >= 0) && (y + dy < HH);
            const float* rp = pl + dy * WW;
            float row[10];
            if (rowok) {
                float4 v0 = *reinterpret_cast<const float4*>(rp);
                float4 v1 = *reinterpret_cast<const float4*>(rp + 4);
                row[0] = xm ? rp[-1] : 0.f;
                row[1] = v0.x; row[2] = v0.y; row[3] = v0.z; row[4] = v0.w;
                row[5] = v1.x; row[6] = v1.y; row[7] = v1.z; row[8] = v1.w;
                row[9] = xp ? rp[8] : 0.f;
            } else {
#pragma unroll
                for (int q = 0; q < 10; ++q) row[q] = 0.f;
            }
#pragma unroll
            for (int o = 0; o < 8; ++o) {
#pragma unroll
                for (int t = 0; t < 3; ++t) {
                    // wave-uniform index -> s_load -> SGPR operand in v_fma
                    float wv = Wf[((o * CC + c) * 3 + r) * 3 + t];
#pragma unroll
                    for (int p = 0; p < 8; ++p) acc[o][p] += wv * row[p + t];
                }
            }
        }
    }

    // normalization: a = aff / sum|aff|; K0 = 1 - sum(a)
    float k0[8];
#pragma unroll
    for (int p = 0; p < 8; ++p) {
        float asum = 0.f;
#pragma unroll
        for (int o = 0; o < 8; ++o) asum += fabsf(acc[o][p]);
        float rinv = 1.0f / asum;
        float s = 0.f;
#pragma unroll
        for (int o = 0; o < 8; ++o) { acc[o][p] *= rinv; s += acc[o][p]; }
        k0[p] = 1.0f - s;
    }

    size_t base = (size_t)b * 9 * HWv + (size_t)y * WW + x0;
    {
        H8 u;
#pragma unroll
        for (int p = 0; p < 8; ++p) u.h[p] = __float2half(k0[p]);
        *reinterpret_cast<float4*>(K + base) = u.f4;
    }
#pragma unroll
    for (int o = 0; o < 8; ++o) {
        H8 u;
#pragma unroll
        for (int p = 0; p < 8; ++p) u.h[p] = __float2half(acc[o][p]);
        *reinterpret_cast<float4*>(K + base + (size_t)(o + 1) * HWv) = u.f4;
    }
}

// ---------------------------------------------------------------------------
// Kernel 2: one propagation iteration, templated on x dtype (R16-proven;
// at the streaming-BW roofline: ~27 MB/launch @ ~6.3 TB/s effective).
// Iter 0: f32 -> fp16;  1..10: fp16 -> fp16;  11: fp16 -> f32 d_out.
// OFFSETS order: (0,0),(0,1),(0,-1),(1,0),(1,1),(1,-1),(-1,0),(-1,1),(-1,-1)
// ---------------------------------------------------------------------------
__device__ __forceinline__ void load_row6(const float* r, bool rowok, bool xm,
                                          bool xpl, float o[6])
{
    if (rowok) {
        float4 v = *reinterpret_cast<const float4*>(r);
        o[0] = xm ? r[-1] : 0.f;
        o[1] = v.x; o[2] = v.y; o[3] = v.z; o[4] = v.w;
        o[5] = xpl ? r[4] : 0.f;
    } else {
#pragma unroll
        for (int q = 0; q < 6; ++q) o[q] = 0.f;
    }
}

__device__ __forceinline__ void load_row6h(const __half* r, bool rowok, bool xm,
                                           bool xpl, float o[6])
{
    if (rowok) {
        H4 u;
        u.s = *reinterpret_cast<const short4*>(r);     // 8 B, aligned (x0%4==0)
        o[0] = xm ? __half2float(r[-1]) : 0.f;
        o[1] = __half2float(u.h[0]); o[2] = __half2float(u.h[1]);
        o[3] = __half2float(u.h[2]); o[4] = __half2float(u.h[3]);
        o[5] = xpl ? __half2float(r[4]) : 0.f;
    } else {
#pragma unroll
        for (int q = 0; q < 6; ++q) o[q] = 0.f;
    }
}

template <typename TI, typename TO>
__global__ __launch_bounds__(256) void prop(const TI* __restrict__ xin,
                                            const __half* __restrict__ K,
                                            TO* __restrict__ xout)
{
    int tid = blockIdx.x * 256 + threadIdx.x;
    const int XT = WW / 4;
    int x4 = tid % XT;
    int t2 = tid / XT;
    int y  = t2 % HH;
    int b  = t2 / HH;
    if (b >= BB) return;
    int x0 = x4 * 4;

    const bool xm  = (x0 > 0);
    const bool xpl = (x0 + 4 < WW);

    const TI* xb = xin + (size_t)b * HWv + (size_t)y * WW + x0;
    float rm[6], r0[6], rp[6];
    if constexpr (sizeof(TI) == 4) {
        load_row6((const float*)xb - WW, y > 0,      xm, xpl, rm);
        load_row6((const float*)xb,      true,       xm, xpl, r0);
        load_row6((const float*)xb + WW, y < HH - 1, xm, xpl, rp);
    } else {
        load_row6h((const __half*)xb - WW, y > 0,      xm, xpl, rm);
        load_row6h((const __half*)xb,      true,       xm, xpl, r0);
        load_row6h((const __half*)xb + WW, y < HH - 1, xm, xpl, rp);
    }

    const __half* Kb = K + (size_t)b * 9 * HWv + (size_t)y * WW + x0;
    float kv[9][4];
#pragma unroll
    for (int k = 0; k < 9; ++k) {
        H4 u;
        u.s = *reinterpret_cast<const short4*>(Kb + (size_t)k * HWv);  // 8 B
#pragma unroll
        for (int p = 0; p < 4; ++p) kv[k][p] = __half2float(u.h[p]);
    }

    float o4[4];
#pragma unroll
    for (int p = 0; p < 4; ++p) {
        o4[p] = kv[0][p] * r0[p + 1]
              + kv[1][p] * r0[p]
              + kv[2][p] * r0[p + 2]
              + kv[3][p] * rm[p + 1]
              + kv[4][p] * rm[p]
              + kv[5][p] * rm[p + 2]
              + kv[6][p] * rp[p + 1]
              + kv[7][p] * rp[p]
              + kv[8][p] * rp[p + 2];
    }

    TO* ob = xout + (size_t)b * HWv + (size_t)y * WW + x0;
    if constexpr (sizeof(TO) == 4) {
        *reinterpret_cast<float4*>((float*)ob) =
            make_float4(o4[0], o4[1], o4[2], o4[3]);
    } else {
        H4 u;
#pragma unroll
        for (int p = 0; p < 4; ++p) u.h[p] = __float2half(o4[p]);
        *reinterpret_cast<short4*>((__half*)ob) = u.s;
    }
}

// ---------------------------------------------------------------------------
extern "C" void kernel_launch(void* const* d_in, const int* in_sizes, int n_in,
                              void* d_out, int out_size, void* d_ws, size_t ws_size,
                              hipStream_t stream) {
    const float* kx   = (const float*)d_in[0];   // [4,32,480,640]
    const float* x_in = (const float*)d_in[1];   // [4,1,480,640]
    const float* Wf   = (const float*)d_in[2];   // [8,32,3,3]
    const float* bf   = (const float*)d_in[3];   // [8]
    float* out  = (float*)d_out;                 // [4,1,480,640]

    __half* Kbuf = (__half*)d_ws;                         // 22.12 MB fp16
    __half* xh0  = Kbuf + (size_t)9 * BB * HWv;           // 2.46 MB fp16
    __half* xh1  = xh0  + (size_t)BB * HWv;               // 2.46 MB fp16
    __half* ping[2] = { xh0, xh1 };

    // conv: 8 px/thread, block=128 -> 1200 blocks (R9 structure, 108 us)
    const int cthreads = BB * HH * (WW / 8);      // 153600
    conv_gen<<<cthreads / 128, 128, 0, stream>>>(kx, Wf, bf, Kbuf);

    // prop: 12 launches; intermediates fp16
    const int pblocks = BB * HH * (WW / 4) / 256; // 1200

    prop<float, __half><<<pblocks, 256, 0, stream>>>(x_in, Kbuf, ping[0]);
    for (int it = 1; it <= 10; ++it) {
        prop<__half, __half><<<pblocks, 256, 0, stream>>>(
            ping[(it - 1) & 1], Kbuf, ping[it & 1]);
    }
    prop<__half, float><<<pblocks, 256, 0, stream>>>(ping[0], Kbuf, out);
}